// Round 8
// baseline (197.133 us; speedup 1.0000x reference)
//
#include <hip/hip_runtime.h>

// R8: attn split over keys in the GRID (ks=2, 1024 keys/block), 64-key
// single-barrier dbuf LDS chunks, per-wave state cut to ~160 regs ->
// __launch_bounds__(256,3) for 3 waves/SIMD (12 waves/CU vs 8). l via
// ones-B MFMA (VALU -> idle MFMA pipe). Partial O/l combined inside ln.
// proj: same single-barrier dbuf treatment (48 KB LDS, 3 blocks/CU).

typedef __attribute__((ext_vector_type(8))) __bf16 bf16x8;
typedef __attribute__((ext_vector_type(4))) float f32x4;

#if __has_builtin(__builtin_amdgcn_exp2f)
#define EXP2F __builtin_amdgcn_exp2f
#else
#define EXP2F exp2f
#endif

#define QSCALE (0.125f * 1.4426950408889634f)  // fold /sqrt(64) and ln->log2

__device__ __forceinline__ unsigned short f2bf(float f) {
  return __builtin_bit_cast(unsigned short, (__bf16)f);
}
__device__ __forceinline__ unsigned pk2(float a, float b) {
  return (unsigned)f2bf(a) | ((unsigned)f2bf(b) << 16);
}
__device__ __forceinline__ f32x4 mfma16(bf16x8 a, bf16x8 b, f32x4 c) {
  return __builtin_amdgcn_mfma_f32_16x16x32_bf16(a, b, c, 0, 0, 0);
}
__device__ __forceinline__ bf16x8 ld_bf8(const unsigned short* p) {
  return *(const bf16x8*)p;
}
// async global->LDS, 16 B per lane; LDS dst is wave-uniform base + lane*16
__device__ __forceinline__ void g2l16(const void* g, void* l) {
  __builtin_amdgcn_global_load_lds(
      (const __attribute__((address_space(1))) void*)g,
      (__attribute__((address_space(3))) void*)l, 16, 0, 0);
}

// ---------------------------------------------------------------------------
// Kernel 1: transpose + convert the three 512x512 weight matrices to bf16,
// layout Wt[z][n][k] (n-major) so MFMA B-fragments read contiguous k.
// ---------------------------------------------------------------------------
__global__ __launch_bounds__(256) void wt_kernel(const float* __restrict__ Wq,
                                                 const float* __restrict__ Wk,
                                                 const float* __restrict__ Wv,
                                                 unsigned short* __restrict__ Wt) {
  int idx = blockIdx.x * 256 + threadIdx.x;
  int o = idx * 8;
  int z = o >> 18;
  int rem = o & 262143;
  int n = rem >> 9;
  int k0 = rem & 511;
  const float* W = (z == 0) ? Wq : ((z == 1) ? Wk : Wv);
  unsigned int w[4];
#pragma unroll
  for (int i = 0; i < 4; ++i) {
    unsigned short lo = f2bf(W[(k0 + 2 * i) * 512 + n]);
    unsigned short hi = f2bf(W[(k0 + 2 * i + 1) * 512 + n]);
    w[i] = (unsigned)lo | ((unsigned)hi << 16);
  }
  *(uint4*)(Wt + o) = make_uint4(w[0], w[1], w[2], w[3]);
}

// ---------------------------------------------------------------------------
// Kernel 2: QKV projection, single-barrier double-buffered staging (LDS 48 KB,
// 3 blocks/CU). Fused padding-mask compute (n0==0 && z<2 blocks). V stored
// transposed with permuted intra-32-key order (pos = quad*8 + sub*4 + r).
// ---------------------------------------------------------------------------
__global__ __launch_bounds__(256, 3) void proj_kernel(
    const float* __restrict__ Xq, const float* __restrict__ Xk,
    const float* __restrict__ Xv, const float* __restrict__ bq,
    const float* __restrict__ bk, const float* __restrict__ bv,
    const unsigned short* __restrict__ Wt, unsigned short* __restrict__ Qb,
    unsigned short* __restrict__ Kb, unsigned short* __restrict__ Vt,
    float* __restrict__ qmask, float* __restrict__ kmask) {
  __shared__ float Asm[2][2][128][16];        // [buf][khalf][row][16] 2x16KB
  __shared__ unsigned short Bsm[2][128][32];  // [buf][row][32]        2x8KB

  int tid = threadIdx.x;
  int m0g = blockIdx.x * 128;
  int z = m0g >> 13;
  int m0 = m0g & 8191;
  int n0 = blockIdx.y * 128;
  const float* X = (z == 0) ? Xq : ((z == 1) ? Xk : Xv);
  const float* bias = (z == 0) ? bq : ((z == 1) ? bk : bv);
  const unsigned short* Wz = Wt + z * 262144;

  int w = tid >> 6, lane = tid & 63;
  int wm = w >> 1, wn = w & 1;
  int mrow = lane & 15, quad = lane >> 4;

  int srow = tid >> 2, schk = tid & 3;
  const float* gA = X + (m0 + srow) * 512 + schk * 4;
  const unsigned short* gB = Wz + (n0 + srow) * 512 + schk * 8;

  f32x4 zero = {0.f, 0.f, 0.f, 0.f};
  f32x4 acc[4][4];
#pragma unroll
  for (int i = 0; i < 4; ++i)
#pragma unroll
    for (int j = 0; j < 4; ++j) acc[i][j] = zero;

  bool domask = (z < 2) && (n0 == 0) && (wn == 0);
  float rsum[4] = {0.f, 0.f, 0.f, 0.f};

  // preload kc=0 into buf 0
  {
    char* lA = (char*)&Asm[0][0][0][0] + tid * 16;
    char* lB = (char*)&Bsm[0][0][0] + tid * 16;
    g2l16(gA, lA);
    g2l16(gA + 64 * 512, lA + 4096);
    g2l16(gA + 16, lA + 8192);
    g2l16(gA + 16 + 64 * 512, lA + 12288);
    g2l16(gB, lB);
    g2l16(gB + 64 * 512, lB + 4096);
  }

  for (int kc = 0; kc < 16; ++kc) {
    int bi = kc & 1;
    __syncthreads();  // drains own staging DMA; buf bi ready for all waves
    if (kc < 15) {
      int ko = (kc + 1) * 32;
      int nb = 1 - bi;
      char* lA = (char*)&Asm[nb][0][0][0] + tid * 16;
      char* lB = (char*)&Bsm[nb][0][0] + tid * 16;
      g2l16(gA + ko, lA);
      g2l16(gA + ko + 64 * 512, lA + 4096);
      g2l16(gA + ko + 16, lA + 8192);
      g2l16(gA + ko + 16 + 64 * 512, lA + 12288);
      g2l16(gB + ko, lB);
      g2l16(gB + ko + 64 * 512, lB + 4096);
    }

    const float* rA = &Asm[bi][quad >> 1][0][(quad & 1) * 8];
    const unsigned short* rB = &Bsm[bi][0][quad * 8];

    bf16x8 af[4], bfr[4];
#pragma unroll
    for (int mt = 0; mt < 4; ++mt) {
      const float* pa = rA + (wm * 64 + mt * 16 + mrow) * 16;
      f32x4 lo = *(const f32x4*)pa;
      f32x4 hi = *(const f32x4*)(pa + 4);
      if (domask)
        rsum[mt] += lo[0] + lo[1] + lo[2] + lo[3] + hi[0] + hi[1] + hi[2] + hi[3];
      bf16x8 t;
      t[0] = (__bf16)lo[0]; t[1] = (__bf16)lo[1];
      t[2] = (__bf16)lo[2]; t[3] = (__bf16)lo[3];
      t[4] = (__bf16)hi[0]; t[5] = (__bf16)hi[1];
      t[6] = (__bf16)hi[2]; t[7] = (__bf16)hi[3];
      af[mt] = t;
    }
#pragma unroll
    for (int nt = 0; nt < 4; ++nt)
      bfr[nt] = ld_bf8(rB + (wn * 64 + nt * 16 + mrow) * 32);
#pragma unroll
    for (int mt = 0; mt < 4; ++mt)
#pragma unroll
      for (int nt = 0; nt < 4; ++nt)
        acc[mt][nt] = mfma16(af[mt], bfr[nt], acc[mt][nt]);
  }

  if (domask) {
    float* msk = (z == 0) ? qmask : kmask;
#pragma unroll
    for (int mt = 0; mt < 4; ++mt) {
      float s = rsum[mt];
      s += __shfl_xor(s, 16);
      s += __shfl_xor(s, 32);
      if (quad == 0)
        msk[m0 + wm * 64 + mt * 16 + mrow] = (s == 0.f) ? 0.f : 1.f;
    }
  }

  if (z < 2) {
    unsigned short* dst = (z == 0) ? Qb : Kb;
    float sc = (z == 0) ? QSCALE : 1.0f;
#pragma unroll
    for (int nt = 0; nt < 4; ++nt) {
      int n = n0 + wn * 64 + nt * 16 + mrow;
      float bv_ = bias[n];
#pragma unroll
      for (int mt = 0; mt < 4; ++mt) {
        int m = m0 + wm * 64 + mt * 16 + quad * 4;
#pragma unroll
        for (int r = 0; r < 4; ++r) {
          float v = fmaxf(acc[mt][nt][r] + bv_, 0.f) * sc;
          dst[(m + r) * 512 + n] = f2bf(v);
        }
      }
    }
  } else {
#pragma unroll
    for (int nt = 0; nt < 4; ++nt) {
      int n = n0 + wn * 64 + nt * 16 + mrow;
      int hh = n >> 6, jj = n & 63;
      float bv_ = bias[n];
#pragma unroll
      for (int mt = 0; mt < 4; ++mt) {
        int grow = m0 + wm * 64 + mt * 16 + quad * 4;
        int bb = grow >> 11, tl = grow & 2047;
        int pos = (tl & ~31) + quad * 8 + (mt & 1) * 4;
        float p0 = fmaxf(acc[mt][nt][0] + bv_, 0.f);
        float p1 = fmaxf(acc[mt][nt][1] + bv_, 0.f);
        float p2 = fmaxf(acc[mt][nt][2] + bv_, 0.f);
        float p3 = fmaxf(acc[mt][nt][3] + bv_, 0.f);
        *(uint2*)(Vt + ((hh * 4 + bb) * 64 + jj) * 2048 + pos) =
            make_uint2(pk2(p0, p1), pk2(p2, p3));
      }
    }
  }
}

// ---------------------------------------------------------------------------
// Kernel 3: attention partial pass. Grid (hb=32, qt=16, ks=2): block = 128 q
// x 1024 keys, 4 waves x 32 q. 16 x 64-key chunks, single barrier/chunk,
// dbuf K/V LDS (32 KB) via XOR-swizzled g2l16. QK: S^T=K*Q^T; PV: O=P*V^T,
// P = register repack (Vt permuted to match); l via ones-B MFMA.
// Writes PARTIAL O (fp32) to Out0/Out1 and l to lsum; no qmask/residual here
// (folded into ln_kernel).
// ---------------------------------------------------------------------------
__global__ __launch_bounds__(256, 3) void attn_kernel(
    const unsigned short* __restrict__ Qb, const unsigned short* __restrict__ Kb,
    const unsigned short* __restrict__ Vt, const float* __restrict__ kmask,
    float* __restrict__ Out0, float* __restrict__ Out1,
    float* __restrict__ lsum) {
  __shared__ unsigned short Ksm[2][4096];  // [buf][64 key][64 dh]
  __shared__ unsigned short Vsm[2][4096];  // [buf][64 dh][64 key-perm]

  int hb = blockIdx.x;
  int qt = blockIdx.y;
  int ks = blockIdx.z;
  int h = hb >> 2, b = hb & 3;
  int q0 = qt * 128;
  int k0 = ks * 1024;
  int tid = threadIdx.x;
  int w = tid >> 6, lane = tid & 63;
  int mrow = lane & 15, quad = lane >> 4;
  int mlow = mrow & 7;

  // staging: row = tid>>3 (0..31; +32 on 2nd issue), slot = (tid&7)^(row&7)
  int srow = tid >> 3;
  int sslot = (tid & 7) ^ (srow & 7);
  const unsigned short* gK = Kb + (b * 2048 + k0 + srow) * 512 + h * 64 + sslot * 8;
  const unsigned short* gV = Vt + (hb * 64 + srow) * 2048 + k0 + sslot * 8;

  // Q B-frags [n=q qn*16+mrow][k=dh kh*32+quad*8]
  bf16x8 qf[2][2];
  {
    const unsigned short* qp =
        Qb + (b * 2048 + q0 + w * 32 + mrow) * 512 + h * 64 + quad * 8;
#pragma unroll
    for (int qn = 0; qn < 2; ++qn) {
      qf[qn][0] = ld_bf8(qp + qn * 8192);
      qf[qn][1] = ld_bf8(qp + qn * 8192 + 32);
    }
  }

  f32x4 zero = {0.f, 0.f, 0.f, 0.f};
  f32x4 oacc[4][2];  // [dt][qn]: col=dh dt*16+mrow, row=q quad*4+r
#pragma unroll
  for (int i = 0; i < 4; ++i) {
    oacc[i][0] = zero;
    oacc[i][1] = zero;
  }
  f32x4 lacc[2] = {zero, zero};
  bf16x8 ones;
#pragma unroll
  for (int i = 0; i < 8; ++i) ones[i] = (__bf16)1.0f;

  // preload chunk 0 into buf 0
  g2l16(gK, &Ksm[0][tid * 8]);
  g2l16(gK + 32 * 512, &Ksm[0][2048 + tid * 8]);
  g2l16(gV, &Vsm[0][tid * 8]);
  g2l16(gV + 32 * 2048, &Vsm[0][2048 + tid * 8]);

  for (int it = 0; it < 16; ++it) {
    int bi = it & 1;
    __syncthreads();  // own staging DMA drained; buf bi ready block-wide
    if (it < 15) {
      int nof = (it + 1) * 64;
      int nb = 1 - bi;
      g2l16(gK + nof * 512, &Ksm[nb][tid * 8]);
      g2l16(gK + (nof + 32) * 512, &Ksm[nb][2048 + tid * 8]);
      g2l16(gV + nof, &Vsm[nb][tid * 8]);
      g2l16(gV + nof + 32 * 2048, &Vsm[nb][2048 + tid * 8]);
    }

    // key masks: keys k0 + it*64 + kg*32 + sub*16 + quad*4 + r
    const float* kmc = kmask + b * 2048 + k0 + it * 64 + quad * 4;
    f32x4 km00 = *(const f32x4*)(kmc);
    f32x4 km01 = *(const f32x4*)(kmc + 16);
    f32x4 km10 = *(const f32x4*)(kmc + 32);
    f32x4 km11 = *(const f32x4*)(kmc + 48);

#pragma unroll
    for (int kg = 0; kg < 2; ++kg) {
      bf16x8 kf00 = ld_bf8(&Ksm[bi][(kg * 32 + mrow) * 64 + ((quad) ^ mlow) * 8]);
      bf16x8 kf01 = ld_bf8(&Ksm[bi][(kg * 32 + mrow) * 64 + ((4 + quad) ^ mlow) * 8]);
      bf16x8 kf10 = ld_bf8(&Ksm[bi][(kg * 32 + 16 + mrow) * 64 + ((quad) ^ mlow) * 8]);
      bf16x8 kf11 = ld_bf8(&Ksm[bi][(kg * 32 + 16 + mrow) * 64 + ((4 + quad) ^ mlow) * 8]);
      bf16x8 vf[4];
#pragma unroll
      for (int dt = 0; dt < 4; ++dt)
        vf[dt] = ld_bf8(&Vsm[bi][(dt * 16 + mrow) * 64 + ((kg * 4 + quad) ^ mlow) * 8]);
      f32x4 kma = kg ? km10 : km00;
      f32x4 kmb = kg ? km11 : km01;

#pragma unroll
      for (int qn = 0; qn < 2; ++qn) {
        f32x4 s0 = mfma16(kf00, qf[qn][0], zero);
        s0 = mfma16(kf01, qf[qn][1], s0);
        f32x4 s1 = mfma16(kf10, qf[qn][0], zero);
        s1 = mfma16(kf11, qf[qn][1], s1);
        f32x4 p0, p1;
#pragma unroll
        for (int r = 0; r < 4; ++r) {
          p0[r] = EXP2F(s0[r]) * kma[r];
          p1[r] = EXP2F(s1[r]) * kmb[r];
        }
        bf16x8 pf = __builtin_bit_cast(
            bf16x8, make_uint4(pk2(p0[0], p0[1]), pk2(p0[2], p0[3]),
                               pk2(p1[0], p1[1]), pk2(p1[2], p1[3])));
        lacc[qn] = mfma16(pf, ones, lacc[qn]);
#pragma unroll
        for (int dt = 0; dt < 4; ++dt)
          oacc[dt][qn] = mfma16(pf, vf[dt], oacc[dt][qn]);
      }
    }
  }

  // --- epilogue: write partial O (fp32) and l
  float* Op = ks ? Out1 : Out0;
#pragma unroll
  for (int qn = 0; qn < 2; ++qn) {
#pragma unroll
    for (int r = 0; r < 4; ++r) {
      int qg = b * 2048 + q0 + w * 32 + qn * 16 + quad * 4 + r;
#pragma unroll
      for (int dt = 0; dt < 4; ++dt)
        Op[qg * 512 + h * 64 + dt * 16 + mrow] = oacc[dt][qn][r];
    }
    if (mrow == 0) {
#pragma unroll
      for (int r = 0; r < 4; ++r)
        lsum[ks * 65536 + hb * 2048 + q0 + w * 32 + qn * 16 + quad * 4 + r] =
            lacc[qn][r];
    }
  }
}

// ---------------------------------------------------------------------------
// Kernel 4: combine partial O + qmask/l scale + residual + LayerNorm.
// One wave per row of 512 (lane covers cols lane*4..+3 and 256+lane*4..+3;
// head = col>>6). out (d_out) holds partial O0 in-place.
// ---------------------------------------------------------------------------
__global__ __launch_bounds__(256) void ln_kernel(
    float* __restrict__ out, const float* __restrict__ O1,
    const float* __restrict__ lsum, const float* __restrict__ qmask,
    const float* __restrict__ queries, const float* __restrict__ gamma,
    const float* __restrict__ beta) {
  int row = blockIdx.x * 4 + (threadIdx.x >> 6);
  int lane = threadIdx.x & 63;
  int b = row >> 11, t = row & 2047;
  int h0 = lane >> 4, h1 = 4 + (lane >> 4);

  float qm = qmask[row];
  float la = lsum[(h0 * 4 + b) * 2048 + t] + lsum[65536 + (h0 * 4 + b) * 2048 + t];
  float lb_ = lsum[(h1 * 4 + b) * 2048 + t] + lsum[65536 + (h1 * 4 + b) * 2048 + t];
  float inva = qm / la, invb = qm / lb_;

  const float* p = out + row * 512;
  float4 o1 = ((const float4*)p)[lane];
  float4 o2 = ((const float4*)p)[64 + lane];
  float4 w1 = ((const float4*)(O1 + row * 512))[lane];
  float4 w2 = ((const float4*)(O1 + row * 512))[64 + lane];
  float4 q1 = ((const float4*)(queries + row * 512))[lane];
  float4 q2 = ((const float4*)(queries + row * 512))[64 + lane];

  float4 v1, v2;
  v1.x = (o1.x + w1.x) * inva + q1.x;
  v1.y = (o1.y + w1.y) * inva + q1.y;
  v1.z = (o1.z + w1.z) * inva + q1.z;
  v1.w = (o1.w + w1.w) * inva + q1.w;
  v2.x = (o2.x + w2.x) * invb + q2.x;
  v2.y = (o2.y + w2.y) * invb + q2.y;
  v2.z = (o2.z + w2.z) * invb + q2.z;
  v2.w = (o2.w + w2.w) * invb + q2.w;

  float s = v1.x + v1.y + v1.z + v1.w + v2.x + v2.y + v2.z + v2.w;
  float sq = v1.x * v1.x + v1.y * v1.y + v1.z * v1.z + v1.w * v1.w +
             v2.x * v2.x + v2.y * v2.y + v2.z * v2.z + v2.w * v2.w;
#pragma unroll
  for (int off = 32; off > 0; off >>= 1) {
    s += __shfl_xor(s, off);
    sq += __shfl_xor(sq, off);
  }
  float mean = s * (1.f / 512.f);
  float var = fmaxf((sq - 512.f * mean * mean) * (1.f / 511.f), 0.f);
  float inv = 1.f / (sqrtf(var) + 1e-8f);

  float4 g1 = ((const float4*)gamma)[lane];
  float4 g2 = ((const float4*)gamma)[64 + lane];
  float4 b1 = ((const float4*)beta)[lane];
  float4 b2 = ((const float4*)beta)[64 + lane];
  v1.x = g1.x * (v1.x - mean) * inv + b1.x;
  v1.y = g1.y * (v1.y - mean) * inv + b1.y;
  v1.z = g1.z * (v1.z - mean) * inv + b1.z;
  v1.w = g1.w * (v1.w - mean) * inv + b1.w;
  v2.x = g2.x * (v2.x - mean) * inv + b2.x;
  v2.y = g2.y * (v2.y - mean) * inv + b2.y;
  v2.z = g2.z * (v2.z - mean) * inv + b2.z;
  v2.w = g2.w * (v2.w - mean) * inv + b2.w;
  float* pw = out + row * 512;
  ((float4*)pw)[lane] = v1;
  ((float4*)pw)[64 + lane] = v2;
}

// ---------------------------------------------------------------------------
extern "C" void kernel_launch(void* const* d_in, const int* in_sizes, int n_in,
                              void* d_out, int out_size, void* d_ws, size_t ws_size,
                              hipStream_t stream) {
  (void)in_sizes; (void)n_in; (void)out_size; (void)ws_size;
  const float* queries = (const float*)d_in[0];
  const float* keys    = (const float*)d_in[1];
  const float* values  = (const float*)d_in[2];
  const float* Wq = (const float*)d_in[3];
  const float* bq = (const float*)d_in[4];
  const float* Wk = (const float*)d_in[5];
  const float* bk = (const float*)d_in[6];
  const float* Wv = (const float*)d_in[7];
  const float* bv = (const float*)d_in[8];
  const float* gamma = (const float*)d_in[9];
  const float* beta  = (const float*)d_in[10];
  float* out = (float*)d_out;

  char* ws = (char*)d_ws;
  unsigned short* Qb = (unsigned short*)(ws);                    // 8 MB
  unsigned short* Kb = (unsigned short*)(ws + 8 * 1024 * 1024);  // 8 MB
  unsigned short* Vt = (unsigned short*)(ws + 16 * 1024 * 1024); // 8 MB
  unsigned short* Wt = (unsigned short*)(ws + 24 * 1024 * 1024); // 1.5 MB
  float* qmask = (float*)(ws + 24 * 1024 * 1024 + 3 * 512 * 512 * 2);
  float* kmask = qmask + 8192;
  float* O1   = (float*)(ws + 26 * 1024 * 1024);                 // 16.78 MB
  float* lsum = (float*)(ws + 26 * 1024 * 1024 + 4 * 2048 * 512 * 4);  // 512 KB

  wt_kernel<<<384, 256, 0, stream>>>(Wq, Wk, Wv, Wt);
  proj_kernel<<<dim3(192, 4), 256, 0, stream>>>(queries, keys, values, bq, bk, bv,
                                                Wt, Qb, Kb, Vt, qmask, kmask);
  attn_kernel<<<dim3(32, 16, 2), 256, 0, stream>>>(Qb, Kb, Vt, kmask, out, O1, lsum);
  ln_kernel<<<2048, 256, 0, stream>>>(out, O1, lsum, qmask, queries, gamma, beta);
}